// Round 1
// 78.726 us; speedup vs baseline: 1.0068x; 1.0068x over previous
//
#include <hip/hip_runtime.h>
#include <math.h>

#define DIM 256
typedef float v2f __attribute__((ext_vector_type(2)));

__device__ __forceinline__ v2f mk2(float a, float b) { v2f r; r.x = a; r.y = b; return r; }

// wave-uniform broadcast lane->SGPR
__device__ __forceinline__ float rl(float v, int l) {
    return __uint_as_float(__builtin_amdgcn_readlane(__float_as_uint(v), l));
}

// VALU-only 16-lane all-reduce step: v += row_ror(v). DPP16 rows (16 lanes)
// coincide with one element's lane group; rotations by 8/4/2/1 give a full
// all-reduce without touching the DS pipe (replaces 32 ds_swizzle shuffles).
// Rotation direction is irrelevant for a sum-all-reduce.
template<int CTRL>
__device__ __forceinline__ float dpp_add(float v) {
    return v + __int_as_float(__builtin_amdgcn_update_dpp(
        0, __float_as_int(v), CTRL, 0xF, 0xF, true));
}

// RY on v2f-index bit B2 of an 8-entry array (amp bit B2+1).
// lo' = c*lo - s*hi ; hi' = s*lo + c*hi   (RY = [[c,-s],[s,c]])
template<int B2>
__device__ __forceinline__ void ry_pk(v2f* v, float c, float s) {
#pragma unroll
    for (int p = 0; p < 8; ++p)
        if (!(p & (1 << B2))) {
            const int q = p | (1 << B2);
            v2f lo = v[p], hi = v[q];
            v[p] = c * lo - s * hi;
            v[q] = s * lo + c * hi;
        }
}

// RY on the in-float2 amp bit — packed: new = (c,c)*v + (-s,s)*swap(v)
// (v_pk_mul_f32 + v_pk_fma_f32 with op_sel-folded swap; was 4 scalar ops/entry)
__device__ __forceinline__ void ry_intra(v2f* v, float c, float s) {
    const v2f cc = mk2(c, c), ns = mk2(-s, s);
#pragma unroll
    for (int p = 0; p < 8; ++p) {
        v2f sw = __builtin_shufflevector(v[p], v[p], 1, 0);
        v[p] = cc * v[p] + ns * sw;   // x: c*lo - s*hi ; y: c*hi + s*lo
    }
}

// One wave = 4 elements (16 lanes/elem, 16 amps = 8 float2/lane).
// Canonical amp idx bits (MSB..LSB): w0 w1 w2 w3 w4 w5 w6 w7.
// Layout B': lane nib = (w2w3w4w5); in-lane v2f p: bit2=w0,bit1=w1,bit0=w6, comp=w7.
// Layout A': lane nib = (w0,w1,w6,w7)=(bit3..bit0); in-lane p: bit2=w2,bit1=w3,bit0=w4, comp=w5.
// LDS per element: 4 chunks (w0w1) * 17 float4 (16 slots + 1 pad) = 272 floats;
// B'-side = 4x float4 @ chunk jhi*68; A'-side = 16x b32, affine offsets i*4.
// Dropped exactly (commute with observables on wires 6,7): weights 18..21, 24, 25,
// and the CZ2 pairs acting only on wires 0..5 (final gates on traced-out wires).
__global__ __launch_bounds__(256, 6) void qae_kernel(const float* __restrict__ x,
                                                     const float* __restrict__ w,
                                                     float* __restrict__ out,
                                                     int batch) {
    __shared__ float lds[4 * 4 * 272];       // 4 waves * 4 elem * 272 floats = 17408 B
    const int lane = threadIdx.x & 63;
    const int wid  = threadIdx.x >> 6;
    const int wave = blockIdx.x * 4 + wid;
    const int nib  = lane & 15;
    const int e    = lane >> 4;
    const int eb   = wave * 4 + e;

    // issue global loads first; trig/mask setup below overlaps the HBM latency
    // (load in B': coalesced, 16 lanes x 16B = 256B per element per chunk)
    v2f v[8];
    if (eb < batch) {
        const float* xp = x + (size_t)eb * DIM + nib * 4;
#pragma unroll
        for (int u = 0; u < 4; ++u) {
            float4 f = *(const float4*)(xp + u * 64);
            v[2 * u]     = mk2(f.x, f.y);
            v[2 * u + 1] = mk2(f.z, f.w);
        }
    } else {
#pragma unroll
        for (int p = 0; p < 8; ++p) v[p] = mk2(0.f, 0.f);
    }

    float* WB = lds + wid * 1088 + e * 272;  // this element's LDS region
    float* pB = WB + nib * 4;                // B'-side float4 base (chunk at +68*jhi)
    float* pA = WB + (nib >> 2) * 68 + (nib & 3);  // A'-side scalar base (amp i at +i*4)

    // in-wave trig: lanes 0..19 -> weights {0..17, 22, 23}
    float h = 0.f;
    if (lane < 20) h = 0.5f * w[lane < 18 ? lane : lane + 4];
    const float cv = __cosf(h), sv = __sinf(h);
#define RYP(B2, slot) ry_pk<B2>(v, rl(cv, slot), rl(sv, slot))
#define RYI(slot)     ry_intra(v, rl(cv, slot), rl(sv, slot))

    // CZ factors. Exponent e = w0*w1 + (w0+w1)*(w2+..+w7).
    // A' (nib = w0w1w6w7): per-amp sign = f(popc(i)) with per-lane gE/gO.
    float gE, gO;
    {
        const int w0 = (nib >> 3) & 1, w1 = (nib >> 2) & 1;
        const float s0 = (__popc(nib & 3) & 1) ? -1.f : 1.f;   // (-1)^(w6+w7)
        if (w0 & w1)      { gE = -1.f; gO = -1.f; }
        else if (w0 ^ w1) { gE = s0;   gO = -s0;  }
        else              { gE = 1.f;  gO = 1.f;  }
    }
    const v2f mAe = mk2(gE, gO), mAo = mk2(gO, gE);
    // B' (nib = w2w3w4w5): pL = (-1)^popc(nib)  (needed for CZ1 only)
    const float pL = (__popc(nib) & 1) ? -1.f : 1.f;
    const v2f mBx0 = mk2(pL, -pL), mBx1 = mk2(-pL, pL);

    // ---- B': layer-0 on wires 0,1,6,7 ----
    RYP(2, 0); RYP(1, 1); RYP(0, 6); RYI(7);

    // ---- T1: B' writes 4 b128, A' reads 16 b32 (wave-private, in-order DS) ----
#pragma unroll
    for (int u = 0; u < 4; ++u)
        *(float4*)(pB + u * 68) = make_float4(v[2*u].x, v[2*u].y, v[2*u+1].x, v[2*u+1].y);
#pragma unroll
    for (int p = 0; p < 8; ++p) {
        v[p].x = pA[p * 8];
        v[p].y = pA[p * 8 + 4];
    }

    // ---- A': layer-0 wires 2,3,4,5 ; CZ0 ; layer-1 wires 2,3,4,5 ----
    RYP(2, 2); RYP(1, 3); RYP(0, 4); RYI(5);
#pragma unroll
    for (int p = 0; p < 8; ++p) v[p] *= (__popc(p) & 1) ? mAo : mAe;
    RYP(2, 10); RYP(1, 11); RYP(0, 12); RYI(13);

    // ---- T2: A' writes 16 b32, B' reads 4 b128 ----
#pragma unroll
    for (int p = 0; p < 8; ++p) {
        pA[p * 8]     = v[p].x;
        pA[p * 8 + 4] = v[p].y;
    }
#pragma unroll
    for (int u = 0; u < 4; ++u) {
        float4 f = *(const float4*)(pB + u * 68);
        v[2 * u] = mk2(f.x, f.y); v[2 * u + 1] = mk2(f.z, f.w);
    }

    // ---- B': layer-1 wires 0,1,6,7 ; CZ1 ; layer-2 wires 0,1,6,7 ; CZ2' ----
    RYP(2, 8); RYP(1, 9); RYP(0, 14); RYI(15);
    v[2] *= mBx0; v[3] *= mBx1; v[4] *= mBx0; v[5] *= mBx1; v[6] = -v[6]; v[7] = -v[7];
    RYP(2, 16); RYP(1, 17); RYP(0, 18); RYI(19);
    // CZ2 reduced to its {0,1}x{6,7} pairs; surviving sign = (w0^w1)&(w6^w7).
    // (All other CZ2 pairs act only on wires 0..5 as the final gates there ->
    //  they commute with the observables and cancel in the expectation.)
    {
        const v2f mPM = mk2(1.f, -1.f), mMP = mk2(-1.f, 1.f);
        v[2] *= mPM; v[3] *= mMP; v[4] *= mPM; v[5] *= mMP;
    }
#undef RYP
#undef RYI

    // ---- epilogue: quads over (w6,w7) per u=(w0w1); norm from state (orthogonal U) ----
    float X6 = 0, X7 = 0, XX = 0, YY = 0, Z6 = 0, Z7 = 0, ZZ = 0, N = 0;
#pragma unroll
    for (int u = 0; u < 4; ++u) {
        float q0 = v[2*u].x, q1 = v[2*u].y, q2 = v[2*u+1].x, q3 = v[2*u+1].y;
        X6 += q0 * q2 + q1 * q3;
        X7 += q0 * q1 + q2 * q3;
        XX += q0 * q3 + q1 * q2;
        YY += q1 * q2 - q0 * q3;
        float t01p = q0*q0 + q1*q1, t01m = q0*q0 - q1*q1;
        float t23p = q2*q2 + q3*q3, t23m = q2*q2 - q3*q3;
        N  += t01p + t23p;
        Z6 += t01p - t23p;
        Z7 += t01m + t23m;
        ZZ += t01m - t23m;
    }
    X6 *= 2.f; X7 *= 2.f; XX *= 2.f; YY *= 2.f;

    // 16-lane all-reduce via DPP row rotations (row_ror:8,4,2,1) — VALU only,
    // no DS pipe, no serial ds_swizzle latency chain in the wave tail.
#define RED(ctrl) \
    N  = dpp_add<ctrl>(N);  X6 = dpp_add<ctrl>(X6); X7 = dpp_add<ctrl>(X7); \
    XX = dpp_add<ctrl>(XX); YY = dpp_add<ctrl>(YY); Z6 = dpp_add<ctrl>(Z6); \
    Z7 = dpp_add<ctrl>(Z7); ZZ = dpp_add<ctrl>(ZZ);
    RED(0x128)  // row_ror:8
    RED(0x124)  // row_ror:4
    RED(0x122)  // row_ror:2
    RED(0x121)  // row_ror:1
#undef RED

    if (eb < batch) {
        // v_rcp_f32: 1 ulp, ample for the 1e-3 tolerance; avoids the precise-div
        // sequence under the divergent store mask.
        const float inv = __builtin_amdgcn_rcpf(N);
        float* o = out + (size_t)eb * 9;
        const int t = nib;
        if (t < 7) {
            float val = (t == 0) ? X6 : (t == 1) ? Z6 : (t == 2) ? X7
                      : (t == 3) ? Z7 : (t == 4) ? XX : (t == 5) ? YY : ZZ;
            int off = t + (t >= 1 ? 1 : 0) + (t >= 3 ? 1 : 0);  // 0,2,3,5,6,7,8
            o[off] = val * inv;
        } else if (t == 7) {
            o[1] = 0.f;                      // <Y6> == 0 exactly (real state)
            o[4] = 0.f;                      // <Y7> == 0 exactly
        }
    }
}

extern "C" void kernel_launch(void* const* d_in, const int* in_sizes, int n_in,
                              void* d_out, int out_size, void* d_ws, size_t ws_size,
                              hipStream_t stream) {
    const float* x = (const float*)d_in[0];
    const float* w = (const float*)d_in[1];
    float* out = (float*)d_out;
    const int batch = in_sizes[0] / DIM;

    const int waves  = (batch + 3) / 4;      // 4 elements per wave
    const int blocks = (waves + 3) / 4;      // 4 waves per 256-thread block
    qae_kernel<<<blocks, 256, 0, stream>>>(x, w, out, batch);
}